// Round 4
// baseline (169.188 us; speedup 1.0000x reference)
//
#include <hip/hip_runtime.h>
#include <hip/hip_bf16.h>
#include <stdint.h>

#define NBATCH 16
#define SEQ 4096
#define DIM 256
#define MEM 40
#define KTOT 512            // interleaved K: k=2d -> x*W1, k=2d+1 -> h*W2
#define MTOT (NBATCH*SEQ)   // 65536 rows

typedef unsigned short u16;
typedef __attribute__((ext_vector_type(8))) short short8;
typedef __attribute__((ext_vector_type(4))) float f32x4;

typedef __attribute__((address_space(1))) const void gvoid_t;
typedef __attribute__((address_space(3))) void lvoid_t;

static __device__ __forceinline__ u16 f2bf(float f) {
    union { float f; uint32_t u; } v; v.f = f;
    uint32_t u = v.u;
    u += 0x7FFFu + ((u >> 16) & 1);   // RTNE (finite values only)
    return (u16)(u >> 16);
}

// ---------------------------------------------------------------------------
// Build B^T (bf16) with interleaved K: BmT32[n*256 + d] = pack(W1[d][n], W2[d][n])
// ---------------------------------------------------------------------------
__global__ __launch_bounds__(256) void k_bmat(const float* __restrict__ W1,
                                              const float* __restrict__ W2,
                                              uint32_t* __restrict__ BmT32) {
    const int n = blockIdx.x;
    const int d = threadIdx.x;
    float w1 = W1[d * DIM + n];
    float w2 = W2[d * DIM + n];
    BmT32[n * DIM + d] = (uint32_t)f2bf(w1) | ((uint32_t)f2bf(w2) << 16);
}

// ---------------------------------------------------------------------------
// FIR conv v3: wp[40] resident in VGPRs; NO history registers, NO shfls.
// Each thread owns channel d, computes 4 outputs per group by re-reading the
// 44-value x window from global (L1/L2-cached, coalesced 256B/load).
// All tap indices compile-time static. sched_barrier(0) every 11 loads caps
// in-flight load results so total live regs ~60 (R0: 80+ regs -> spills @64;
// R2: lane-split -> 48 shfl/16 outputs serial chain, both ~45-58us).
// Writes interleaved bf16 A rows (x|h) into Aout (== d_out reused as scratch).
// ---------------------------------------------------------------------------
#define TC 32

template <bool GUARD>
__device__ __forceinline__ void conv_body(const float* __restrict__ xb,
                                          uint32_t* __restrict__ Ab,
                                          const float (&wp)[MEM],
                                          int t0, float& colsum) {
    for (int it = 0; it < TC / 4; ++it) {
        const int tb = t0 + it * 4;
        const float* bp = xb + (size_t)(tb - MEM) * DIM;
        float h0 = 0.f, h1 = 0.f, h2 = 0.f, h3 = 0.f;
        float c0 = 0.f, c1 = 0.f, c2 = 0.f, c3 = 0.f;
#pragma unroll
        for (int j = 0; j <= MEM + 3; ++j) {
            float v;
            if (GUARD) {
                int m = tb - MEM + j;
                int mc = m < 0 ? 0 : m;
                v = xb[(size_t)mc * DIM];
                v = m < 0 ? 0.f : v;
            } else {
                v = bp[(size_t)j * DIM];
            }
            const int moff = j - MEM;
            if (moff == 0) c0 = v;
            if (moff == 1) c1 = v;
            if (moff == 2) c2 = v;
            if (moff == 3) c3 = v;
            { int l = 0 - moff; if (l >= 1 && l <= MEM) h0 = fmaf(wp[l - 1], v, h0); }
            { int l = 1 - moff; if (l >= 1 && l <= MEM) h1 = fmaf(wp[l - 1], v, h1); }
            { int l = 2 - moff; if (l >= 1 && l <= MEM) h2 = fmaf(wp[l - 1], v, h2); }
            { int l = 3 - moff; if (l >= 1 && l <= MEM) h3 = fmaf(wp[l - 1], v, h3); }
            if ((j % 11) == 10) __builtin_amdgcn_sched_barrier(0);
        }
        colsum += c0 + c1 + c2 + c3;
        __hip_bfloat162 p0 = __float22bfloat162_rn(make_float2(c0, h0));
        __hip_bfloat162 p1 = __float22bfloat162_rn(make_float2(c1, h1));
        __hip_bfloat162 p2 = __float22bfloat162_rn(make_float2(c2, h2));
        __hip_bfloat162 p3 = __float22bfloat162_rn(make_float2(c3, h3));
        Ab[(size_t)(tb + 0) * DIM] = *reinterpret_cast<uint32_t*>(&p0);
        Ab[(size_t)(tb + 1) * DIM] = *reinterpret_cast<uint32_t*>(&p1);
        Ab[(size_t)(tb + 2) * DIM] = *reinterpret_cast<uint32_t*>(&p2);
        Ab[(size_t)(tb + 3) * DIM] = *reinterpret_cast<uint32_t*>(&p3);
    }
}

__global__ void k_conv(const float* __restrict__ x,
                       const float* __restrict__ mw,
                       uint32_t* __restrict__ Aout,
                       float* __restrict__ total) {
    const int d  = threadIdx.x;          // 256 channels
    const int b  = blockIdx.y;
    const int t0 = blockIdx.x * TC;

    const float mw0 = mw[d];
    float wp[MEM];
#pragma unroll
    for (int l = 0; l < MEM; ++l) wp[l] = mw[(l + 1) * DIM + d] - mw0;

    const float* xb = x + (size_t)b * SEQ * DIM + d;
    uint32_t* Ab    = Aout + (size_t)b * SEQ * DIM + d;

    float colsum = 0.0f;
    if (t0 >= MEM)
        conv_body<false>(xb, Ab, wp, t0, colsum);
    else
        conv_body<true>(xb, Ab, wp, t0, colsum);

    atomicAdd(&total[b * DIM + d], colsum);
}

// ---------------------------------------------------------------------------
// corr[b][n] = bias[n] + sum_d mw[0][d] * total[b][d] * W2[d][n]
// ---------------------------------------------------------------------------
__global__ __launch_bounds__(256) void k_corr(const float* __restrict__ W2,
                                              const float* __restrict__ bias,
                                              const float* __restrict__ mw,
                                              const float* __restrict__ total,
                                              float* __restrict__ corr) {
    const int b = blockIdx.x;
    const int n = threadIdx.x;
    float s = bias[n];
    for (int dd = 0; dd < DIM; ++dd)
        s += mw[dd] * total[b * DIM + dd] * W2[dd * DIM + n];
    corr[b * DIM + n] = s;
}

// ---------------------------------------------------------------------------
// GEMM: out[M=65536, N=256] = A[M, 512](bf16) @ Bmat[512, 256](bf16) + corr[b]
// BM=128, BN=256 (full width -> block reads only its own A rows, so A may live
// in d_out), BK=64, 8 waves (2x4), 16x16x32 bf16 MFMA, 4x4 frags per wave.
// ---------------------------------------------------------------------------
#define BM 128
#define BN 256
#define BK 64

__global__ __launch_bounds__(512) void k_gemm(const u16* A,
                                              const u16* __restrict__ BmT,
                                              const float* __restrict__ corr,
                                              float* out) {
    __shared__ __align__(16) u16 Alds[BM * BK];   // 16 KB, [row][k]
    __shared__ __align__(16) u16 Blds[BN * BK];   // 32 KB, [col][k]

    const int tid  = threadIdx.x;
    const int lane = tid & 63;
    const int w    = tid >> 6;     // 0..7
    const int wr   = w >> 2;       // 0..1  (M split)
    const int wc   = w & 3;        // 0..3  (N split)
    const int m0   = blockIdx.x * BM;

    f32x4 acc[4][4] = {};

    for (int kt = 0; kt < KTOT / BK; ++kt) {
        const int k0 = kt * BK;
        // ---- stage A tile [128][64] : 1024 x 16B chunks, 2 per thread
#pragma unroll
        for (int i = 0; i < 2; ++i) {
            int c   = i * 512 + tid;
            int row = c >> 3;
            int kin = (c & 7) * 8;
            const u16* g = A + ((size_t)(m0 + row) * KTOT + k0 + kin);
            char* l = (char*)Alds + (size_t)(i * 512 + (tid & ~63)) * 16;
            __builtin_amdgcn_global_load_lds((gvoid_t*)g, (lvoid_t*)l, 16, 0, 0);
        }
        // ---- stage B tile [256 cols][64 k] from BmT[n][k] : 2048 chunks, 4/thread
#pragma unroll
        for (int i = 0; i < 4; ++i) {
            int c   = i * 512 + tid;
            int n   = c >> 3;
            int kin = (c & 7) * 8;
            const u16* g = BmT + ((size_t)n * KTOT + k0 + kin);
            char* l = (char*)Blds + (size_t)(i * 512 + (tid & ~63)) * 16;
            __builtin_amdgcn_global_load_lds((gvoid_t*)g, (lvoid_t*)l, 16, 0, 0);
        }
        __syncthreads();

#pragma unroll
        for (int kk = 0; kk < 2; ++kk) {
            short8 af[4], bfr[4];
#pragma unroll
            for (int mi = 0; mi < 4; ++mi) {
                int r = wr * 64 + mi * 16 + (lane & 15);
                af[mi] = *(const short8*)(Alds + r * BK + kk * 32 + ((lane >> 4) * 8));
            }
#pragma unroll
            for (int ni = 0; ni < 4; ++ni) {
                int ccol = wc * 64 + ni * 16 + (lane & 15);
                bfr[ni] = *(const short8*)(Blds + ccol * BK + kk * 32 + ((lane >> 4) * 8));
            }
#pragma unroll
            for (int mi = 0; mi < 4; ++mi)
#pragma unroll
                for (int ni = 0; ni < 4; ++ni)
                    acc[mi][ni] = __builtin_amdgcn_mfma_f32_16x16x32_bf16(
                        af[mi], bfr[ni], acc[mi][ni], 0, 0, 0);
        }
        __syncthreads();
    }

    // ---- epilogue: out = acc + corr[b][col]
    const int bidx = m0 >> 12;           // 4096 rows per batch, BM=128 divides it
    const float* corr_b = corr + bidx * DIM;
#pragma unroll
    for (int ni = 0; ni < 4; ++ni) {
        int col = wc * 64 + ni * 16 + (lane & 15);
        float cv = corr_b[col];
#pragma unroll
        for (int mi = 0; mi < 4; ++mi) {
            int rbase = m0 + wr * 64 + mi * 16 + ((lane >> 4) * 4);
#pragma unroll
            for (int j = 0; j < 4; ++j)
                out[(size_t)(rbase + j) * DIM + col] = acc[mi][ni][j] + cv;
        }
    }
}

// ---------------------------------------------------------------------------
extern "C" void kernel_launch(void* const* d_in, const int* in_sizes, int n_in,
                              void* d_out, int out_size, void* d_ws, size_t ws_size,
                              hipStream_t stream) {
    const float* x    = (const float*)d_in[0];
    const float* W1   = (const float*)d_in[1];
    const float* W2   = (const float*)d_in[2];
    const float* bias = (const float*)d_in[3];
    const float* mw   = (const float*)d_in[4];
    float* out = (float*)d_out;

    // ws layout: BmT (256*512*2 = 256KB) | total (16KB) | corr (16KB)
    u16*   BmT   = (u16*)d_ws;
    float* total = (float*)((char*)d_ws + 262144);
    float* corr  = (float*)((char*)d_ws + 262144 + 16384);

    hipMemsetAsync(total, 0, NBATCH * DIM * sizeof(float), stream);
    k_bmat<<<dim3(DIM), dim3(256), 0, stream>>>(W1, W2, (uint32_t*)BmT);
    k_conv<<<dim3(SEQ / TC, NBATCH), dim3(256), 0, stream>>>(
        x, mw, (uint32_t*)d_out, total);
    k_corr<<<dim3(NBATCH), dim3(256), 0, stream>>>(W2, bias, mw, total, corr);
    k_gemm<<<dim3(MTOT / BM), dim3(512), 0, stream>>>(
        (const u16*)d_out, BmT, corr, out);
}

// Round 5
// 126.630 us; speedup vs baseline: 1.3361x; 1.3361x over previous
//
#include <hip/hip_runtime.h>
#include <hip/hip_bf16.h>
#include <stdint.h>

#define NBATCH 16
#define SEQ 4096
#define DIM 256
#define MEM 40
#define KTOT 512            // interleaved K: k=2d -> x*W1, k=2d+1 -> h*W2
#define MTOT (NBATCH*SEQ)   // 65536 rows

typedef unsigned short u16;
typedef __attribute__((ext_vector_type(8))) short short8;
typedef __attribute__((ext_vector_type(4))) float f32x4;

typedef __attribute__((address_space(1))) const void gvoid_t;
typedef __attribute__((address_space(3))) void lvoid_t;

static __device__ __forceinline__ u16 f2bf(float f) {
    union { float f; uint32_t u; } v; v.f = f;
    uint32_t u = v.u;
    u += 0x7FFFu + ((u >> 16) & 1);   // RTNE (finite values only)
    return (u16)(u >> 16);
}

// ---------------------------------------------------------------------------
// Build B^T (bf16) with interleaved K: BmT32[n*256 + d] = pack(W1[d][n], W2[d][n])
// ---------------------------------------------------------------------------
__global__ __launch_bounds__(256) void k_bmat(const float* __restrict__ W1,
                                              const float* __restrict__ W2,
                                              uint32_t* __restrict__ BmT32) {
    const int n = blockIdx.x;
    const int d = threadIdx.x;
    float w1 = W1[d * DIM + n];
    float w2 = W2[d * DIM + n];
    BmT32[n * DIM + d] = (uint32_t)f2bf(w1) | ((uint32_t)f2bf(w2) << 16);
}

// ---------------------------------------------------------------------------
// FIR conv v4: x window lives in LDS (R0: 80+ regs -> spills; R2: lane-split
// serial shfls; R3: global re-read -> 4.8x HBM over-fetch, all slower).
// Block = 64 channels x 128 timesteps. Stage x[t0-40 .. t0+128) x 64ch into
// LDS [168][64] f32 (43KB, 3 blocks/CU). Thread (c, tseg) holds wp[40] + 4
// accumulators (~60 VGPR, no spills) and re-reads the 44-value window per
// 4 outputs via ds_read_b32 at static immediate offsets (row-broadcast,
// 2-way bank alias = free). Writes interleaved bf16 (x|h) into Aout.
// ---------------------------------------------------------------------------
#define CGRP 64
#define TBLK 128
#define THALO (TBLK + MEM)   // 168 rows

__global__ void k_conv(const float* __restrict__ x,
                       const float* __restrict__ mw,
                       uint32_t* __restrict__ Aout,
                       float* __restrict__ total) {
    __shared__ float xs[THALO * CGRP];          // [row][c]

    const int tid = threadIdx.x;
    const int b   = blockIdx.y;
    const int dg  = blockIdx.z;
    const int t0  = blockIdx.x * TBLK;
    const int d0  = dg * CGRP;

    // ---- stage [t0-40, t0+TBLK) x 64 channels, float2, coalesced ----
    const float* xbase = x + (size_t)b * SEQ * DIM + d0;
    float2* xs2 = (float2*)xs;
    if (t0 >= MEM) {
        const float* src = xbase + (size_t)(t0 - MEM) * DIM;
#pragma unroll
        for (int k = 0; k < (THALO * CGRP / 2) / 256; ++k) {   // 21
            int f = tid + k * 256;
            int row = f >> 5, c2 = f & 31;
            xs2[f] = *(const float2*)(src + (size_t)row * DIM + c2 * 2);
        }
    } else {
#pragma unroll
        for (int k = 0; k < 21; ++k) {
            int f = tid + k * 256;
            int row = f >> 5, c2 = f & 31;
            int t = t0 - MEM + row;
            float2 v = make_float2(0.f, 0.f);
            if (t >= 0) v = *(const float2*)(xbase + (size_t)t * DIM + c2 * 2);
            xs2[f] = v;
        }
    }
    __syncthreads();

    const int c    = tid & (CGRP - 1);   // lane == channel -> stores coalesced
    const int tseg = tid >> 6;           // 4 segments of 32 timesteps
    const int d    = d0 + c;

    const float mw0 = mw[d];
    float wp[MEM];
#pragma unroll
    for (int l = 0; l < MEM; ++l) wp[l] = mw[(l + 1) * DIM + d] - mw0;

    uint32_t* Ab = Aout + ((size_t)b * SEQ + t0 + tseg * 32) * DIM + d;
    const float* seg = xs + (size_t)(tseg * 32) * CGRP + c;   // row 0 == t-40

    float colsum = 0.0f;
    for (int ch4 = 0; ch4 < 8; ++ch4) {          // 8 chunks of 4 outputs
        const float* pw = seg + (size_t)(ch4 * 4) * CGRP;
        float h0 = 0.f, h1 = 0.f, h2 = 0.f, h3 = 0.f;
        float c0 = 0.f, c1 = 0.f, c2 = 0.f, c3 = 0.f;
#pragma unroll
        for (int j = 0; j <= MEM + 3; ++j) {     // static 256B-imm LDS reads
            float v = pw[(size_t)j * CGRP];
            const int moff = j - MEM;
            if (moff == 0) c0 = v;
            if (moff == 1) c1 = v;
            if (moff == 2) c2 = v;
            if (moff == 3) c3 = v;
            { int l = 0 - moff; if (l >= 1 && l <= MEM) h0 = fmaf(wp[l - 1], v, h0); }
            { int l = 1 - moff; if (l >= 1 && l <= MEM) h1 = fmaf(wp[l - 1], v, h1); }
            { int l = 2 - moff; if (l >= 1 && l <= MEM) h2 = fmaf(wp[l - 1], v, h2); }
            { int l = 3 - moff; if (l >= 1 && l <= MEM) h3 = fmaf(wp[l - 1], v, h3); }
        }
        colsum += c0 + c1 + c2 + c3;
        __hip_bfloat162 p0 = __float22bfloat162_rn(make_float2(c0, h0));
        __hip_bfloat162 p1 = __float22bfloat162_rn(make_float2(c1, h1));
        __hip_bfloat162 p2 = __float22bfloat162_rn(make_float2(c2, h2));
        __hip_bfloat162 p3 = __float22bfloat162_rn(make_float2(c3, h3));
        const int tb = ch4 * 4;
        Ab[(size_t)(tb + 0) * DIM] = *reinterpret_cast<uint32_t*>(&p0);
        Ab[(size_t)(tb + 1) * DIM] = *reinterpret_cast<uint32_t*>(&p1);
        Ab[(size_t)(tb + 2) * DIM] = *reinterpret_cast<uint32_t*>(&p2);
        Ab[(size_t)(tb + 3) * DIM] = *reinterpret_cast<uint32_t*>(&p3);
    }
    atomicAdd(&total[b * DIM + d], colsum);
}

// ---------------------------------------------------------------------------
// corr[b][n] = bias[n] + sum_d mw[0][d] * total[b][d] * W2[d][n]
// ---------------------------------------------------------------------------
__global__ __launch_bounds__(256) void k_corr(const float* __restrict__ W2,
                                              const float* __restrict__ bias,
                                              const float* __restrict__ mw,
                                              const float* __restrict__ total,
                                              float* __restrict__ corr) {
    const int b = blockIdx.x;
    const int n = threadIdx.x;
    float s = bias[n];
    for (int dd = 0; dd < DIM; ++dd)
        s += mw[dd] * total[b * DIM + dd] * W2[dd * DIM + n];
    corr[b * DIM + n] = s;
}

// ---------------------------------------------------------------------------
// GEMM: out[M=65536, N=256] = A[M, 512](bf16) @ Bmat[512, 256](bf16) + corr[b]
// BM=128, BN=256, BK=64, 8 waves, 16x16x32 MFMA. XCD-aware bijective swizzle
// (512 blocks, 512%8==0) for L2 locality on the memory-bound A stream.
// ---------------------------------------------------------------------------
#define BM 128
#define BN 256
#define BK 64

__global__ __launch_bounds__(512) void k_gemm(const u16* A,
                                              const u16* __restrict__ BmT,
                                              const float* __restrict__ corr,
                                              float* out) {
    __shared__ __align__(16) u16 Alds[BM * BK];   // 16 KB, [row][k]
    __shared__ __align__(16) u16 Blds[BN * BK];   // 32 KB, [col][k]

    const int tid  = threadIdx.x;
    const int lane = tid & 63;
    const int w    = tid >> 6;     // 0..7
    const int wr   = w >> 2;       // 0..1  (M split)
    const int wc   = w & 3;        // 0..3  (N split)
    // XCD swizzle: 512 blocks -> 64 contiguous tiles per XCD
    const int bid  = blockIdx.x;
    const int swz  = (bid & 7) * 64 + (bid >> 3);
    const int m0   = swz * BM;

    f32x4 acc[4][4] = {};

    for (int kt = 0; kt < KTOT / BK; ++kt) {
        const int k0 = kt * BK;
        // ---- stage A tile [128][64] : 1024 x 16B chunks, 2 per thread
#pragma unroll
        for (int i = 0; i < 2; ++i) {
            int c   = i * 512 + tid;
            int row = c >> 3;
            int kin = (c & 7) * 8;
            const u16* g = A + ((size_t)(m0 + row) * KTOT + k0 + kin);
            char* l = (char*)Alds + (size_t)(i * 512 + (tid & ~63)) * 16;
            __builtin_amdgcn_global_load_lds((gvoid_t*)g, (lvoid_t*)l, 16, 0, 0);
        }
        // ---- stage B tile [256 cols][64 k] from BmT[n][k] : 2048 chunks, 4/thread
#pragma unroll
        for (int i = 0; i < 4; ++i) {
            int c   = i * 512 + tid;
            int n   = c >> 3;
            int kin = (c & 7) * 8;
            const u16* g = BmT + ((size_t)n * KTOT + k0 + kin);
            char* l = (char*)Blds + (size_t)(i * 512 + (tid & ~63)) * 16;
            __builtin_amdgcn_global_load_lds((gvoid_t*)g, (lvoid_t*)l, 16, 0, 0);
        }
        __syncthreads();

#pragma unroll
        for (int kk = 0; kk < 2; ++kk) {
            short8 af[4], bfr[4];
#pragma unroll
            for (int mi = 0; mi < 4; ++mi) {
                int r = wr * 64 + mi * 16 + (lane & 15);
                af[mi] = *(const short8*)(Alds + r * BK + kk * 32 + ((lane >> 4) * 8));
            }
#pragma unroll
            for (int ni = 0; ni < 4; ++ni) {
                int ccol = wc * 64 + ni * 16 + (lane & 15);
                bfr[ni] = *(const short8*)(Blds + ccol * BK + kk * 32 + ((lane >> 4) * 8));
            }
#pragma unroll
            for (int mi = 0; mi < 4; ++mi)
#pragma unroll
                for (int ni = 0; ni < 4; ++ni)
                    acc[mi][ni] = __builtin_amdgcn_mfma_f32_16x16x32_bf16(
                        af[mi], bfr[ni], acc[mi][ni], 0, 0, 0);
        }
        __syncthreads();
    }

    // ---- epilogue: out = acc + corr[b][col]
    const int bidx = m0 >> 12;           // 4096 rows per batch, BM=128 divides it
    const float* corr_b = corr + bidx * DIM;
#pragma unroll
    for (int ni = 0; ni < 4; ++ni) {
        int col = wc * 64 + ni * 16 + (lane & 15);
        float cv = corr_b[col];
#pragma unroll
        for (int mi = 0; mi < 4; ++mi) {
            int rbase = m0 + wr * 64 + mi * 16 + ((lane >> 4) * 4);
#pragma unroll
            for (int j = 0; j < 4; ++j)
                out[(size_t)(rbase + j) * DIM + col] = acc[mi][ni][j] + cv;
        }
    }
}

// ---------------------------------------------------------------------------
extern "C" void kernel_launch(void* const* d_in, const int* in_sizes, int n_in,
                              void* d_out, int out_size, void* d_ws, size_t ws_size,
                              hipStream_t stream) {
    const float* x    = (const float*)d_in[0];
    const float* W1   = (const float*)d_in[1];
    const float* W2   = (const float*)d_in[2];
    const float* bias = (const float*)d_in[3];
    const float* mw   = (const float*)d_in[4];
    float* out = (float*)d_out;

    // ws layout: BmT (256*512*2 = 256KB) | total (16KB) | corr (16KB)
    u16*   BmT   = (u16*)d_ws;
    float* total = (float*)((char*)d_ws + 262144);
    float* corr  = (float*)((char*)d_ws + 262144 + 16384);

    hipMemsetAsync(total, 0, NBATCH * DIM * sizeof(float), stream);
    k_bmat<<<dim3(DIM), dim3(256), 0, stream>>>(W1, W2, (uint32_t*)BmT);
    k_conv<<<dim3(SEQ / TBLK, NBATCH, DIM / CGRP), dim3(256), 0, stream>>>(
        x, mw, (uint32_t*)d_out, total);
    k_corr<<<dim3(NBATCH), dim3(256), 0, stream>>>(W2, bias, mw, total, corr);
    k_gemm<<<dim3(MTOT / BM), dim3(512), 0, stream>>>(
        (const u16*)d_out, BmT, corr, out);
}